// Round 3
// baseline (865.277 us; speedup 1.0000x reference)
//
#include <hip/hip_runtime.h>

typedef short v8s __attribute__((ext_vector_type(8)));
typedef float v4f __attribute__((ext_vector_type(4)));

// problem constants
#define NCH    64
#define NHH    128
#define NWW    128
#define NOC    64
#define KSTEPS 18          // 576 / 32

// LDS slab layout: [6 rows][66 cols][72 c (64 + 8 pad)] bf16
#define CSTR 72
#define COLS 66

__device__ __forceinline__ unsigned short f2bf(float f) {
  unsigned int u = __float_as_uint(f);
  u += 0x7FFFu + ((u >> 16) & 1u);           // round-to-nearest-even
  return (unsigned short)(u >> 16);
}

// ---------------------------------------------------------------------------
// Pack expert weights into MFMA B-fragment-linear bf16:
// element (((e*18+s)*4+nt)*64+lane)*8+j  =  W[k = s*32+(lane>>4)*8+j][n = nt*16+(lane&15)]
// with k = (kh*3+kw)*64 + c  and W[k][n] = expert_w[e][n][c][kh][kw]
// Total elements: 8*18*4*64*8 = 294912
// ---------------------------------------------------------------------------
__global__ void pack_b_kernel(const float* __restrict__ ew,
                              unsigned short* __restrict__ bp) {
  int f = blockIdx.x * 256 + threadIdx.x;    // 0 .. 294911
  int j = f & 7;
  int t = f >> 3;
  int lane = t & 63;
  t >>= 6;
  int nt = t & 3;
  t >>= 2;                                   // t = e*18 + s, 0..143
  int s = t % KSTEPS;
  int e = t / KSTEPS;
  int k = s * 32 + (lane >> 4) * 8 + j;
  int n = nt * 16 + (lane & 15);
  int khw = k >> 6;
  int c = k & 63;
  bp[f] = f2bf(ew[((e * NOC + n) * NCH + c) * 9 + khw]);
}

// ---------------------------------------------------------------------------
// Gating: one block per patch (b, ph, pw). fp32 dot + softmax, float4 loads.
// ---------------------------------------------------------------------------
__global__ void gate_kernel(const float* __restrict__ x,
                            const float* __restrict__ gw,
                            const float* __restrict__ gb,
                            float* __restrict__ gate_out) {
  int pid = blockIdx.x;
  int pw = pid & 15;
  int ph = (pid >> 4) & 15;
  int b  = pid >> 8;
  int tid = threadIdx.x;

  float cy = (ph + 0.5f) / 16.0f;
  float cx = (pw + 0.5f) / 16.0f;

  float acc[8];
#pragma unroll
  for (int e = 0; e < 8; ++e) acc[e] = 0.f;

  // image part: 64 ch x 16 float4 groups = 1024 units
  for (int u = tid; u < 1024; u += 256) {
    int ch = u >> 4;
    int pix = (u & 15) * 4;
    int py = pix >> 3;
    int px = pix & 7;
    const float4 xv = *(const float4*)&x[((b * NCH + ch) * NHH + ph * 8 + py) * NWW + pw * 8 + px];
    int fidx = ch * 64 + pix;
#pragma unroll
    for (int e = 0; e < 8; ++e) {
      const float4 wv = *(const float4*)&gw[e * 6144 + fidx];
      acc[e] += xv.x * wv.x + xv.y * wv.y + xv.z * wv.z + xv.w * wv.w;
    }
  }
  // positional part: feature value is constant over the 64 patch pixels
  for (int u = tid; u < 512; u += 256) {
    int j = u >> 4;
    int g4 = (u & 15) * 4;
    float freq = (float)(1 << (j & 7)) * 3.14159265358979323846f;
    float base = (j < 16) ? cy : cx;
    float a = base * freq;
    float v = ((j >> 3) & 1) ? cosf(a) : sinf(a);
    int fidx = 4096 + j * 64 + g4;
#pragma unroll
    for (int e = 0; e < 8; ++e) {
      const float4 wv = *(const float4*)&gw[e * 6144 + fidx];
      acc[e] += v * (wv.x + wv.y + wv.z + wv.w);
    }
  }

#pragma unroll
  for (int e = 0; e < 8; ++e)
    for (int off = 32; off > 0; off >>= 1)
      acc[e] += __shfl_down(acc[e], off, 64);

  __shared__ float red[8][4];
  int wid = tid >> 6;
  int lane = tid & 63;
  if (lane == 0) {
#pragma unroll
    for (int e = 0; e < 8; ++e) red[e][wid] = acc[e];
  }
  __syncthreads();
  if (tid == 0) {
    float lg[8];
    float mx = -1e30f;
#pragma unroll
    for (int e = 0; e < 8; ++e) {
      lg[e] = red[e][0] + red[e][1] + red[e][2] + red[e][3] + gb[e];
      mx = fmaxf(mx, lg[e]);
    }
    float sum = 0.f;
#pragma unroll
    for (int e = 0; e < 8; ++e) { lg[e] = expf(lg[e] - mx); sum += lg[e]; }
    float inv = 1.0f / sum;
#pragma unroll
    for (int e = 0; e < 8; ++e) gate_out[pid * 8 + e] = lg[e] * inv;
  }
}

// ---------------------------------------------------------------------------
// Main fused kernel: block = 4 waves (256 thr), covers 4 rows x 64 cols x 64 oc.
// Wave (rp, och): rows hq*4 + rp*2 + {0,1}, oc half och (32 oc), M=128 N=32.
// B fragments prefetched into a 3-deep register ring (wave-private, no K-loop
// barriers). A fragments: sliding-window ds_read_b128 from the x slab.
// ---------------------------------------------------------------------------
__global__ __launch_bounds__(256, 2) void moe_conv_kernel(
    const float* __restrict__ x,
    const float* __restrict__ eb,
    const unsigned short* __restrict__ bp,
    const float* __restrict__ gate,
    float* __restrict__ out) {
  __shared__ __align__(16) unsigned short slab[6 * COLS * CSTR];  // 57024 B
  __shared__ float ldsg[64];                                      // [pw_local 8][e 8]

  const int tid = threadIdx.x;
  const int bid = blockIdx.x;
  const int wseg = bid & 1;
  const int hq = (bid >> 1) & 31;
  const int b = bid >> 6;
  const int w0 = wseg * 64;
  const int wid = tid >> 6;
  const int lane = tid & 63;
  const int quad = lane >> 4;
  const int l15 = lane & 15;
  const int rp  = wid >> 1;         // row-pair within block
  const int och = wid & 1;          // oc half
  const int ntb = och * 2;          // base n-tile (nt = ntb, ntb+1)

  // --- B prologue prefetch: global steps 0,1,2 (overlaps slab staging) ---
  const v8s* bpv = (const v8s*)bp;
  v8s ring0[2], ring1[2], ring2[2];
  ring0[0] = bpv[(0 * 4 + ntb) * 64 + lane];
  ring0[1] = bpv[(0 * 4 + ntb + 1) * 64 + lane];
  ring1[0] = bpv[(1 * 4 + ntb) * 64 + lane];
  ring1[1] = bpv[(1 * 4 + ntb + 1) * 64 + lane];
  ring2[0] = bpv[(2 * 4 + ntb) * 64 + lane];
  ring2[1] = bpv[(2 * 4 + ntb + 1) * 64 + lane];

  // gates for this block's 8 patches (all 4 rows are in one patch row)
  if (tid < 64) {
    ldsg[tid] = gate[((b * 16 + (hq >> 1)) * 16 + wseg * 8 + (tid >> 3)) * 8 + (tid & 7)];
  }

  // --- stage x slab: rows hq*4-1 .. hq*4+4, cols w0-1 .. w0+64, all c ---
  const int hbase = hq * 4 - 1;
  const int wbase = w0 - 1;
  for (int flat = tid; flat < 6 * 32 * COLS; flat += 256) {
    int col = flat % COLS;
    int t = flat / COLS;
    int cp = t & 31;                    // channel pair
    int r = t >> 5;                     // slab row 0..5
    int gh = hbase + r;
    int gw_ = wbase + col;
    float v0 = 0.f, v1 = 0.f;
    if (((unsigned)gh < 128u) && ((unsigned)gw_ < 128u)) {
      const float* px = x + (((b * NCH + cp * 2) * NHH + gh) * NWW + gw_);
      v0 = px[0];
      v1 = px[NHH * NWW];
    }
    unsigned int pk = (unsigned int)f2bf(v0) | ((unsigned int)f2bf(v1) << 16);
    *(unsigned int*)&slab[(r * COLS + col) * CSTR + cp * 2] = pk;
  }
  __syncthreads();

  const v4f vzero = {0.f, 0.f, 0.f, 0.f};
  v4f oacc[8][2];
#pragma unroll
  for (int mt = 0; mt < 8; ++mt) {
    oacc[mt][0] = vzero;
    oacc[mt][1] = vzero;
  }

  // wave-constant part of the A-frag LDS address
  const unsigned short* abase = &slab[(rp * 2 * COLS + l15) * CSTR + quad * 8];

  for (int e = 0; e < 8; ++e) {
    v4f vacc[8][2];
#pragma unroll
    for (int mt = 0; mt < 8; ++mt) {
      vacc[mt][0] = vzero;
      vacc[mt][1] = vzero;
    }

#pragma unroll
    for (int s = 0; s < KSTEPS; ++s) {
      const int kh = s / 6;
      const int kw = (s / 2) % 3;
      const int ch = s & 1;
      v8s b0, b1;
      if ((s % 3) == 0) { b0 = ring0[0]; b1 = ring0[1]; }
      else if ((s % 3) == 1) { b0 = ring1[0]; b1 = ring1[1]; }
      else { b0 = ring2[0]; b1 = ring2[1]; }
#pragma unroll
      for (int mt = 0; mt < 8; ++mt) {
        // row_local = rp*2 + (mt>>2) + kh ; col = (mt&3)*16 + l15 + kw
        const v8s a = *(const v8s*)(abase +
            (((mt >> 2) + kh) * COLS + (mt & 3) * 16 + kw) * CSTR + ch * 32);
        vacc[mt][0] = __builtin_amdgcn_mfma_f32_16x16x32_bf16(a, b0, vacc[mt][0], 0, 0, 0);
        vacc[mt][1] = __builtin_amdgcn_mfma_f32_16x16x32_bf16(a, b1, vacc[mt][1], 0, 0, 0);
      }
      // prefetch global step es+3 into the slot just consumed
      int pes = e * KSTEPS + s + 3;
      pes = pes > 143 ? 143 : pes;
      if ((s % 3) == 0) {
        ring0[0] = bpv[(pes * 4 + ntb) * 64 + lane];
        ring0[1] = bpv[(pes * 4 + ntb + 1) * 64 + lane];
      } else if ((s % 3) == 1) {
        ring1[0] = bpv[(pes * 4 + ntb) * 64 + lane];
        ring1[1] = bpv[(pes * 4 + ntb + 1) * 64 + lane];
      } else {
        ring2[0] = bpv[(pes * 4 + ntb) * 64 + lane];
        ring2[1] = bpv[(pes * 4 + ntb + 1) * 64 + lane];
      }
    }

    // epilogue: bias + relu + gate, accumulate into oacc
    float bias0 = eb[e * NOC + ntb * 16 + l15];
    float bias1 = eb[e * NOC + (ntb + 1) * 16 + l15];
#pragma unroll
    for (int mt = 0; mt < 8; ++mt) {
      float g = ldsg[((mt & 3) * 2 + (quad >> 1)) * 8 + e];
#pragma unroll
      for (int r = 0; r < 4; ++r) {
        float v0 = fmaxf(vacc[mt][0][r] + bias0, 0.f);
        float v1 = fmaxf(vacc[mt][1][r] + bias1, 0.f);
        oacc[mt][0][r] += v0 * g;
        oacc[mt][1][r] += v1 * g;
      }
    }
  }

  // direct coalesced-ish stores: per (mt,nt) one v4f per lane
  const int h0 = hq * 4 + rp * 2;
#pragma unroll
  for (int i = 0; i < 2; ++i) {
    const int oc = (ntb + i) * 16 + l15;
#pragma unroll
    for (int mt = 0; mt < 8; ++mt) {
      const int h = h0 + (mt >> 2);
      float* dst = out + ((b * NOC + oc) * NHH + h) * NWW + w0 + (mt & 3) * 16 + quad * 4;
      *(v4f*)dst = oacc[mt][i];
    }
  }
}

// ---------------------------------------------------------------------------
extern "C" void kernel_launch(void* const* d_in, const int* in_sizes, int n_in,
                              void* d_out, int out_size, void* d_ws, size_t ws_size,
                              hipStream_t stream) {
  const float* x  = (const float*)d_in[0];
  const float* ew = (const float*)d_in[1];
  const float* eb = (const float*)d_in[2];
  const float* gw = (const float*)d_in[3];
  const float* gb = (const float*)d_in[4];
  float* out = (float*)d_out;

  unsigned short* bp = (unsigned short*)d_ws;              // 294912 bf16 = 589824 B
  float* gate = (float*)((char*)d_ws + 589824);            // 4096*8 fp32 = 131072 B

  hipLaunchKernelGGL(pack_b_kernel, dim3(1152), dim3(256), 0, stream, ew, bp);
  hipLaunchKernelGGL(gate_kernel, dim3(4096), dim3(256), 0, stream, x, gw, gb, gate);
  hipLaunchKernelGGL(moe_conv_kernel, dim3(1024), dim3(256), 0, stream, x, eb, bp, gate, out);
}

// Round 4
// 303.647 us; speedup vs baseline: 2.8496x; 2.8496x over previous
//
#include <hip/hip_runtime.h>

typedef short v8s __attribute__((ext_vector_type(8)));
typedef float v4f __attribute__((ext_vector_type(4)));

// problem constants
#define NCH    64
#define NHH    128
#define NWW    128
#define NOC    64
#define KSTEPS 18          // 576 / 32

// LDS slab layout: [6 rows][66 cols][72 c (64 + 8 pad)] bf16
#define CSTR 72
#define COLS 66
#define SLAB_BYTES (6 * COLS * CSTR * 2)     // 57024
#define BBUF_OFF   SLAB_BYTES                // B double-buffer at 57024
#define LDSG_OFF   (SLAB_BYTES + 16384)      // gates at 73408
#define SMEM_BYTES 73728

__device__ __forceinline__ unsigned short f2bf(float f) {
  unsigned int u = __float_as_uint(f);
  u += 0x7FFFu + ((u >> 16) & 1u);           // round-to-nearest-even
  return (unsigned short)(u >> 16);
}

// ---------------------------------------------------------------------------
// Pack expert weights into MFMA B-fragment-linear bf16:
// element (((e*18+s)*4+nt)*64+lane)*8+j  =  W[k = s*32+(lane>>4)*8+j][n = nt*16+(lane&15)]
// with k = (kh*3+kw)*64 + c  and W[k][n] = expert_w[e][n][c][kh][kw]
// Total elements: 8*18*4*64*8 = 294912
// ---------------------------------------------------------------------------
__global__ void pack_b_kernel(const float* __restrict__ ew,
                              unsigned short* __restrict__ bp) {
  int f = blockIdx.x * 256 + threadIdx.x;    // 0 .. 294911
  int j = f & 7;
  int t = f >> 3;
  int lane = t & 63;
  t >>= 6;
  int nt = t & 3;
  t >>= 2;                                   // t = e*18 + s, 0..143
  int s = t % KSTEPS;
  int e = t / KSTEPS;
  int k = s * 32 + (lane >> 4) * 8 + j;
  int n = nt * 16 + (lane & 15);
  int khw = k >> 6;
  int c = k & 63;
  bp[f] = f2bf(ew[((e * NOC + n) * NCH + c) * 9 + khw]);
}

// ---------------------------------------------------------------------------
// Gating: one block per patch (b, ph, pw). fp32 dot + softmax, float4 loads.
// ---------------------------------------------------------------------------
__global__ void gate_kernel(const float* __restrict__ x,
                            const float* __restrict__ gw,
                            const float* __restrict__ gb,
                            float* __restrict__ gate_out) {
  int pid = blockIdx.x;
  int pw = pid & 15;
  int ph = (pid >> 4) & 15;
  int b  = pid >> 8;
  int tid = threadIdx.x;

  float cy = (ph + 0.5f) / 16.0f;
  float cx = (pw + 0.5f) / 16.0f;

  float acc[8];
#pragma unroll
  for (int e = 0; e < 8; ++e) acc[e] = 0.f;

  // image part: 64 ch x 16 float4 groups = 1024 units
  for (int u = tid; u < 1024; u += 256) {
    int ch = u >> 4;
    int pix = (u & 15) * 4;
    int py = pix >> 3;
    int px = pix & 7;
    const float4 xv = *(const float4*)&x[((b * NCH + ch) * NHH + ph * 8 + py) * NWW + pw * 8 + px];
    int fidx = ch * 64 + pix;
#pragma unroll
    for (int e = 0; e < 8; ++e) {
      const float4 wv = *(const float4*)&gw[e * 6144 + fidx];
      acc[e] += xv.x * wv.x + xv.y * wv.y + xv.z * wv.z + xv.w * wv.w;
    }
  }
  // positional part: feature value is constant over the 64 patch pixels
  for (int u = tid; u < 512; u += 256) {
    int j = u >> 4;
    int g4 = (u & 15) * 4;
    float freq = (float)(1 << (j & 7)) * 3.14159265358979323846f;
    float base = (j < 16) ? cy : cx;
    float a = base * freq;
    float v = ((j >> 3) & 1) ? cosf(a) : sinf(a);
    int fidx = 4096 + j * 64 + g4;
#pragma unroll
    for (int e = 0; e < 8; ++e) {
      const float4 wv = *(const float4*)&gw[e * 6144 + fidx];
      acc[e] += v * (wv.x + wv.y + wv.z + wv.w);
    }
  }

#pragma unroll
  for (int e = 0; e < 8; ++e)
    for (int off = 32; off > 0; off >>= 1)
      acc[e] += __shfl_down(acc[e], off, 64);

  __shared__ float red[8][4];
  int wid = tid >> 6;
  int lane = tid & 63;
  if (lane == 0) {
#pragma unroll
    for (int e = 0; e < 8; ++e) red[e][wid] = acc[e];
  }
  __syncthreads();
  if (tid == 0) {
    float lg[8];
    float mx = -1e30f;
#pragma unroll
    for (int e = 0; e < 8; ++e) {
      lg[e] = red[e][0] + red[e][1] + red[e][2] + red[e][3] + gb[e];
      mx = fmaxf(mx, lg[e]);
    }
    float sum = 0.f;
#pragma unroll
    for (int e = 0; e < 8; ++e) { lg[e] = expf(lg[e] - mx); sum += lg[e]; }
    float inv = 1.0f / sum;
#pragma unroll
    for (int e = 0; e < 8; ++e) gate_out[pid * 8 + e] = lg[e] * inv;
  }
}

// ---------------------------------------------------------------------------
// Async-stage one B stage (2 k-steps = 8 KB) into LDS double buffer `buf`.
// Each wave DMAs its 2 KB quarter with two global_load_lds width-16 ops.
// ---------------------------------------------------------------------------
__device__ __forceinline__ void load_stage(const unsigned short* __restrict__ bp,
                                           char* smem, int gs, int buf,
                                           int wid, int lane) {
  const char* gsrc = (const char*)bp + gs * 8192 + wid * 2048 + lane * 16;
  char* ldst = smem + BBUF_OFF + buf * 8192 + wid * 2048;   // wave-uniform base
  __builtin_amdgcn_global_load_lds(
      (const __attribute__((address_space(1))) void*)gsrc,
      (__attribute__((address_space(3))) void*)ldst, 16, 0, 0);
  __builtin_amdgcn_global_load_lds(
      (const __attribute__((address_space(1))) void*)(gsrc + 1024),
      (__attribute__((address_space(3))) void*)(ldst + 1024), 16, 0, 0);
}

// ---------------------------------------------------------------------------
// Main fused kernel: block = 4 waves (256 thr), covers 4 rows x 64 cols x 64 oc.
// Wave (rp, och): rows hq*4 + rp*2 + {0,1}, oc half och (32 oc) -> M=128 N=32.
// B staged block-shared in LDS (2-deep dbuf, global_load_lds), barrier-paced
// 72 stages of 2 k-steps. A: sliding-window ds_read_b128 from the x slab.
// ---------------------------------------------------------------------------
__global__ __launch_bounds__(256, 2) void moe_conv_kernel(
    const float* __restrict__ x,
    const float* __restrict__ eb,
    const unsigned short* __restrict__ bp,
    const float* __restrict__ gate,
    float* __restrict__ out) {
  __shared__ __align__(16) char smem[SMEM_BYTES];
  unsigned short* slab = (unsigned short*)smem;
  unsigned short* bbufs = (unsigned short*)(smem + BBUF_OFF);
  float* ldsg = (float*)(smem + LDSG_OFF);   // [pw_local 8][e 8]

  const int tid = threadIdx.x;
  const int bid = blockIdx.x;
  const int wseg = bid & 1;
  const int hq = (bid >> 1) & 31;
  const int b = bid >> 6;
  const int w0 = wseg * 64;
  const int wid = tid >> 6;
  const int lane = tid & 63;
  const int quad = lane >> 4;
  const int l15 = lane & 15;
  const int rp  = wid >> 1;         // row-pair within block
  const int och = wid & 1;          // oc half
  const int ntb = och * 2;          // base n-tile

  // kick off B stage 0 DMA immediately (overlaps slab staging)
  load_stage(bp, smem, 0, 0, wid, lane);

  // gates for this block's 8 patches (4 rows = one patch row hq/2)
  if (tid < 64) {
    ldsg[tid] = gate[((b * 16 + (hq >> 1)) * 16 + wseg * 8 + (tid >> 3)) * 8 + (tid & 7)];
  }

  // --- stage x slab: rows hq*4-1 .. hq*4+4, cols w0-1 .. w0+64, all c ---
  const int hbase = hq * 4 - 1;
  const int wbase = w0 - 1;
  for (int flat = tid; flat < 6 * 32 * COLS; flat += 256) {
    int col = flat % COLS;
    int t = flat / COLS;
    int cp = t & 31;                    // channel pair
    int r = t >> 5;                     // slab row 0..5
    int gh = hbase + r;
    int gw_ = wbase + col;
    float v0 = 0.f, v1 = 0.f;
    if (((unsigned)gh < 128u) && ((unsigned)gw_ < 128u)) {
      const float* px = x + (((b * NCH + cp * 2) * NHH + gh) * NWW + gw_);
      v0 = px[0];
      v1 = px[NHH * NWW];
    }
    unsigned int pk = (unsigned int)f2bf(v0) | ((unsigned int)f2bf(v1) << 16);
    *(unsigned int*)&slab[(r * COLS + col) * CSTR + cp * 2] = pk;
  }
  __syncthreads();    // slab ready + B stage 0 landed

  const v4f vzero = {0.f, 0.f, 0.f, 0.f};
  v4f oacc[8][2];
#pragma unroll
  for (int mt = 0; mt < 8; ++mt) {
    oacc[mt][0] = vzero;
    oacc[mt][1] = vzero;
  }

  // wave-constant part of the A-frag LDS address
  const unsigned short* abase = &slab[(rp * 2 * COLS + l15) * CSTR + quad * 8];

  for (int e = 0; e < 8; ++e) {
    v4f vacc[8][2];
#pragma unroll
    for (int mt = 0; mt < 8; ++mt) {
      vacc[mt][0] = vzero;
      vacc[mt][1] = vzero;
    }

#pragma unroll
    for (int st = 0; st < 9; ++st) {
      const int gs = e * 9 + st;        // flat stage 0..71
      if (gs > 0) __syncthreads();      // stage gs data ready; gs-1 consumed
      if (gs + 1 < 72) load_stage(bp, smem, gs + 1, (gs + 1) & 1, wid, lane);

      const unsigned short* bstage = bbufs + (gs & 1) * 4096;
#pragma unroll
      for (int sub = 0; sub < 2; ++sub) {
        const int sl = st * 2 + sub;    // expert-local k-step 0..17
        const int kh = sl / 6;
        const int kw = (sl / 2) % 3;
        const int ch = sl & 1;
        const v8s b0 = *(const v8s*)(bstage + (sub * 4 + ntb) * 512 + lane * 8);
        const v8s b1 = *(const v8s*)(bstage + (sub * 4 + ntb + 1) * 512 + lane * 8);
#pragma unroll
        for (int mt = 0; mt < 8; ++mt) {
          // row_local = rp*2 + (mt>>2) + kh ; col = (mt&3)*16 + l15 + kw
          const v8s a = *(const v8s*)(abase +
              (((mt >> 2) + kh) * COLS + (mt & 3) * 16 + kw) * CSTR + ch * 32);
          vacc[mt][0] = __builtin_amdgcn_mfma_f32_16x16x32_bf16(a, b0, vacc[mt][0], 0, 0, 0);
          vacc[mt][1] = __builtin_amdgcn_mfma_f32_16x16x32_bf16(a, b1, vacc[mt][1], 0, 0, 0);
        }
      }
    }

    // epilogue: bias + relu + gate, accumulate into oacc (wave-private)
    float bias0 = eb[e * NOC + ntb * 16 + l15];
    float bias1 = eb[e * NOC + (ntb + 1) * 16 + l15];
#pragma unroll
    for (int mt = 0; mt < 8; ++mt) {
      float g = ldsg[((mt & 3) * 2 + (quad >> 1)) * 8 + e];
#pragma unroll
      for (int r = 0; r < 4; ++r) {
        float v0 = fmaxf(vacc[mt][0][r] + bias0, 0.f);
        float v1 = fmaxf(vacc[mt][1][r] + bias1, 0.f);
        oacc[mt][0][r] += v0 * g;
        oacc[mt][1][r] += v1 * g;
      }
    }
  }

  // ---- transpose through LDS (per-wave region) for full-line stores ----
  __syncthreads();                      // everyone done with slab/B buffers
  float* tb = (float*)smem + wid * 4352;  // [row:2][oc:32][68] floats = 17408 B
#pragma unroll
  for (int i = 0; i < 2; ++i)
#pragma unroll
    for (int mt = 0; mt < 8; ++mt)
      *(v4f*)(tb + (mt >> 2) * 2176 + (i * 16 + l15) * 68 + (mt & 3) * 16 + quad * 4) =
          oacc[mt][i];
  // wave-private region: in-wave lgkmcnt ordering suffices, no barrier

  const int h0 = hq * 4 + rp * 2;
#pragma unroll
  for (int r2 = 0; r2 < 2; ++r2) {
    const int h = h0 + r2;
#pragma unroll
    for (int g4 = 0; g4 < 8; ++g4) {
      const int ocl = g4 * 4 + quad;            // 0..31 within this oc half
      const v4f vv = *(const v4f*)(tb + r2 * 2176 + ocl * 68 + l15 * 4);
      float* dst = out + ((b * NOC + och * 32 + ocl) * NHH + h) * NWW + w0 + l15 * 4;
      *(v4f*)dst = vv;
    }
  }
}

// ---------------------------------------------------------------------------
extern "C" void kernel_launch(void* const* d_in, const int* in_sizes, int n_in,
                              void* d_out, int out_size, void* d_ws, size_t ws_size,
                              hipStream_t stream) {
  const float* x  = (const float*)d_in[0];
  const float* ew = (const float*)d_in[1];
  const float* eb = (const float*)d_in[2];
  const float* gw = (const float*)d_in[3];
  const float* gb = (const float*)d_in[4];
  float* out = (float*)d_out;

  unsigned short* bp = (unsigned short*)d_ws;              // 294912 bf16 = 589824 B
  float* gate = (float*)((char*)d_ws + 589824);            // 4096*8 fp32 = 131072 B

  hipLaunchKernelGGL(pack_b_kernel, dim3(1152), dim3(256), 0, stream, ew, bp);
  hipLaunchKernelGGL(gate_kernel, dim3(4096), dim3(256), 0, stream, x, gw, gb, gate);
  hipLaunchKernelGGL(moe_conv_kernel, dim3(1024), dim3(256), 0, stream, x, eb, bp, gate, out);
}